// Round 1
// baseline (87.377 us; speedup 1.0000x reference)
//
#include <hip/hip_runtime.h>

#define NB 16      // batch
#define NC 128     // bands
#define NR 64      // resolution
#define NF 128     // frames
#define NS 32768   // samples
#define TS 64      // samples per tile in mix kernel

// Kernel A: per (b,c) row — softmax over resolution, then matvec with
// resonance (R x F) -> framesT stored TRANSPOSED as (f, b, c) so the mix
// kernel can stage frame columns with coalesced loads.
__global__ __launch_bounds__(64) void frames_kernel(
    const float* __restrict__ x,         // (B, C, R)
    const float* __restrict__ resonance, // (R, F)
    float* __restrict__ framesT)         // (F, B*C)
{
    const int row = blockIdx.x;   // b*128 + c
    const int r   = threadIdx.x;  // 0..63  (one wave)

    float xv = x[row * NR + r];

    // wave-64 max reduction
    float m = xv;
    #pragma unroll
    for (int off = 32; off >= 1; off >>= 1)
        m = fmaxf(m, __shfl_xor(m, off, 64));
    float e = __expf(xv - m);
    float ssum = e;
    #pragma unroll
    for (int off = 32; off >= 1; off >>= 1)
        ssum += __shfl_xor(ssum, off, 64);
    float p = e / ssum;

    __shared__ float psh[NR];
    psh[r] = p;
    __syncthreads();

    // thread r computes frames for f = r and f = r + 64
    float acc0 = 0.f, acc1 = 0.f;
    #pragma unroll 8
    for (int rr = 0; rr < NR; ++rr) {
        float pr = psh[rr];
        acc0 = fmaf(pr, resonance[rr * NF + r],      acc0);
        acc1 = fmaf(pr, resonance[rr * NF + r + 64], acc1);
    }
    framesT[r        * (NB * NC) + row] = acc0;
    framesT[(r + 64) * (NB * NC) + row] = acc1;
}

// Kernel B: tile of TS=64 samples per block; i0/i1 are uniform per tile.
// Stage frames[:, :, i0] and [:, :, i1] (16 KB) in LDS, stream filter_bank
// exactly once from global, accumulate all 16 batches.
// Thread layout: sg = tid&31 -> 2 consecutive samples; bg = tid>>5 -> 2 bands.
__global__ __launch_bounds__(256) void mix_kernel(
    const float* __restrict__ framesT, // (F, B*C)
    const float* __restrict__ fbank,   // (C, S)
    float* __restrict__ out)           // (B, S)
{
    __shared__ float g0[NB * NC];
    __shared__ float g1[NB * NC];

    const int base = blockIdx.x * TS;
    const int tid  = threadIdx.x;

    // tile-uniform frame indices
    float posb = (base + 0.5f) * (1.0f / 256.0f) - 0.5f;
    int i0 = (int)floorf(posb);
    i0 = i0 < 0 ? 0 : (i0 > NF - 1 ? NF - 1 : i0);
    int i1 = (i0 + 1 < NF) ? i0 + 1 : NF - 1;

    for (int t = tid; t < NB * NC; t += 256) {
        g0[t] = framesT[i0 * (NB * NC) + t];
        g1[t] = framesT[i1 * (NB * NC) + t];
    }
    __syncthreads();

    const int sg = tid & 31;
    const int bg = tid >> 5;
    const int s0 = base + sg * 2;
    const int b0 = bg * 2;

    float pos0 = (s0 + 0.5f) * (1.0f / 256.0f) - 0.5f;
    float pos1 = (s0 + 1.5f) * (1.0f / 256.0f) - 0.5f;
    pos0 = fminf(fmaxf(pos0, 0.f), (float)(NF - 1));
    pos1 = fminf(fmaxf(pos1, 0.f), (float)(NF - 1));
    const float w0 = pos0 - (float)i0;
    const float w1 = pos1 - (float)i0;

    // acc[frame-sel][band][sample]
    float a000 = 0.f, a001 = 0.f, a010 = 0.f, a011 = 0.f; // frame i0
    float a100 = 0.f, a101 = 0.f, a110 = 0.f, a111 = 0.f; // frame i1

    const float* g0b0 = &g0[b0 * NC];
    const float* g0b1 = &g0[(b0 + 1) * NC];
    const float* g1b0 = &g1[b0 * NC];
    const float* g1b1 = &g1[(b0 + 1) * NC];

    #pragma unroll 4
    for (int c = 0; c < NC; ++c) {
        float2 fv = *(const float2*)&fbank[c * NS + s0];
        float q00 = g0b0[c], q01 = g0b1[c];
        float q10 = g1b0[c], q11 = g1b1[c];
        a000 = fmaf(q00, fv.x, a000); a001 = fmaf(q00, fv.y, a001);
        a010 = fmaf(q01, fv.x, a010); a011 = fmaf(q01, fv.y, a011);
        a100 = fmaf(q10, fv.x, a100); a101 = fmaf(q10, fv.y, a101);
        a110 = fmaf(q11, fv.x, a110); a111 = fmaf(q11, fv.y, a111);
    }

    const float inv = 1.0f / (float)NC;
    out[b0 * NS + s0]           = ((1.f - w0) * a000 + w0 * a100) * inv;
    out[b0 * NS + s0 + 1]       = ((1.f - w1) * a001 + w1 * a101) * inv;
    out[(b0 + 1) * NS + s0]     = ((1.f - w0) * a010 + w0 * a110) * inv;
    out[(b0 + 1) * NS + s0 + 1] = ((1.f - w1) * a011 + w1 * a111) * inv;
}

extern "C" void kernel_launch(void* const* d_in, const int* in_sizes, int n_in,
                              void* d_out, int out_size, void* d_ws, size_t ws_size,
                              hipStream_t stream) {
    const float* x    = (const float*)d_in[0]; // (16,128,64)
    const float* res  = (const float*)d_in[1]; // (64,128)
    const float* fbk  = (const float*)d_in[2]; // (1,128,32768)
    float* out        = (float*)d_out;         // (16,1,32768)
    float* framesT    = (float*)d_ws;          // (128,16,128) = 1 MB

    frames_kernel<<<NB * NC, 64, 0, stream>>>(x, res, framesT);
    mix_kernel<<<NS / TS, 256, 0, stream>>>(framesT, fbk, out);
}

// Round 2
// 85.753 us; speedup vs baseline: 1.0189x; 1.0189x over previous
//
#include <hip/hip_runtime.h>

#define NB 16      // batch
#define NC 128     // bands
#define NR 64      // resolution
#define NF 128     // frames
#define NS 32768   // samples
#define TS 64      // samples per tile in mix kernel

// Kernel A: per (b,c) row — softmax over resolution, then matvec with
// resonance (R x F) -> framesT stored TRANSPOSED as (f, b, c) so the mix
// kernel can stage frame columns with coalesced float4 loads.
__global__ __launch_bounds__(64) void frames_kernel(
    const float* __restrict__ x,         // (B, C, R)
    const float* __restrict__ resonance, // (R, F)
    float* __restrict__ framesT)         // (F, B*C)
{
    const int row = blockIdx.x;   // b*128 + c
    const int r   = threadIdx.x;  // 0..63  (one wave)

    float xv = x[row * NR + r];

    // wave-64 max reduction
    float m = xv;
    #pragma unroll
    for (int off = 32; off >= 1; off >>= 1)
        m = fmaxf(m, __shfl_xor(m, off, 64));
    float e = __expf(xv - m);
    float ssum = e;
    #pragma unroll
    for (int off = 32; off >= 1; off >>= 1)
        ssum += __shfl_xor(ssum, off, 64);
    float p = e / ssum;

    __shared__ float psh[NR];
    psh[r] = p;
    __syncthreads();

    // thread r computes frames for f = r and f = r + 64
    float acc0 = 0.f, acc1 = 0.f;
    #pragma unroll 8
    for (int rr = 0; rr < NR; ++rr) {
        float pr = psh[rr];
        acc0 = fmaf(pr, resonance[rr * NF + r],      acc0);
        acc1 = fmaf(pr, resonance[rr * NF + r + 64], acc1);
    }
    framesT[r        * (NB * NC) + row] = acc0;
    framesT[(r + 64) * (NB * NC) + row] = acc1;
}

// Kernel B: tile of TS=64 samples per block; i0/i1 are uniform per tile
// (verified: floor((s+0.5)/256-0.5) is constant over an aligned 64-run).
// Stage frames[:, :, i0] / [:, :, i1] (16 KB) in LDS via float4, stream
// filter_bank exactly once, 4 samples x 1 batch per thread.
__global__ __launch_bounds__(256) void mix_kernel(
    const float* __restrict__ framesT, // (F, B*C)
    const float* __restrict__ fbank,   // (C, S)
    float* __restrict__ out)           // (B, S)
{
    __shared__ float g0[NB * NC];
    __shared__ float g1[NB * NC];

    const int base = blockIdx.x * TS;
    const int tid  = threadIdx.x;

    // tile-uniform frame indices
    float posb = (base + 0.5f) * (1.0f / 256.0f) - 0.5f;
    int i0 = (int)floorf(posb);
    i0 = i0 < 0 ? 0 : (i0 > NF - 1 ? NF - 1 : i0);
    const int i1 = (i0 + 1 < NF) ? i0 + 1 : NF - 1;

    {   // stage 2 x 8 KB with float4 (2048 floats = 512 float4 each)
        const float4* src0 = (const float4*)(framesT + (size_t)i0 * (NB * NC));
        const float4* src1 = (const float4*)(framesT + (size_t)i1 * (NB * NC));
        float4* dst0 = (float4*)g0;
        float4* dst1 = (float4*)g1;
        dst0[tid]       = src0[tid];
        dst0[tid + 256] = src0[tid + 256];
        dst1[tid]       = src1[tid];
        dst1[tid + 256] = src1[tid + 256];
    }
    __syncthreads();

    const int sg = tid & 15;   // sample group: 16 x 4 = 64 samples
    const int b  = tid >> 4;   // batch 0..15
    const int s0 = base + sg * 4;

    float w[4];
    #pragma unroll
    for (int j = 0; j < 4; ++j) {
        float p = (s0 + j + 0.5f) * (1.0f / 256.0f) - 0.5f;
        p = fminf(fmaxf(p, 0.f), (float)(NF - 1));
        w[j] = p - (float)i0;
    }

    float a0[4] = {0.f, 0.f, 0.f, 0.f};
    float a1[4] = {0.f, 0.f, 0.f, 0.f};
    const float* gb0 = &g0[b * NC];
    const float* gb1 = &g1[b * NC];

    #pragma unroll 4
    for (int c = 0; c < NC; ++c) {
        float4 fv = *(const float4*)&fbank[c * NS + s0];
        float q0 = gb0[c];
        float q1 = gb1[c];
        a0[0] = fmaf(q0, fv.x, a0[0]);
        a0[1] = fmaf(q0, fv.y, a0[1]);
        a0[2] = fmaf(q0, fv.z, a0[2]);
        a0[3] = fmaf(q0, fv.w, a0[3]);
        a1[0] = fmaf(q1, fv.x, a1[0]);
        a1[1] = fmaf(q1, fv.y, a1[1]);
        a1[2] = fmaf(q1, fv.z, a1[2]);
        a1[3] = fmaf(q1, fv.w, a1[3]);
    }

    const float inv = 1.0f / (float)NC;
    float4 r;
    r.x = ((1.f - w[0]) * a0[0] + w[0] * a1[0]) * inv;
    r.y = ((1.f - w[1]) * a0[1] + w[1] * a1[1]) * inv;
    r.z = ((1.f - w[2]) * a0[2] + w[2] * a1[2]) * inv;
    r.w = ((1.f - w[3]) * a0[3] + w[3] * a1[3]) * inv;
    *(float4*)&out[b * NS + s0] = r;
}

extern "C" void kernel_launch(void* const* d_in, const int* in_sizes, int n_in,
                              void* d_out, int out_size, void* d_ws, size_t ws_size,
                              hipStream_t stream) {
    const float* x    = (const float*)d_in[0]; // (16,128,64)
    const float* res  = (const float*)d_in[1]; // (64,128)
    const float* fbk  = (const float*)d_in[2]; // (1,128,32768)
    float* out        = (float*)d_out;         // (16,1,32768)
    float* framesT    = (float*)d_ws;          // (128,16,128) = 1 MB

    frames_kernel<<<NB * NC, 64, 0, stream>>>(x, res, framesT);
    mix_kernel<<<NS / TS, 256, 0, stream>>>(framesT, fbk, out);
}